// Round 16
// baseline (62.199 us; speedup 1.0000x reference)
//
#include <hip/hip_runtime.h>

// FairINV 2-layer GCN + linear head — linear collapse + bucket-binned propagation.
//   w2c = W2@Wc; w1c = W1@w2c; c1 = b1.w2c; c2 = b2.Wc + bc      (prep, 1 block)
//   gemv_bin: bin edges by bucket dst>>8 (512 bin units, reg-staged, FIRST)
//             || z0 = x@w1c (GEMV, branchless 4-row ILP)
//   bindeg:   bins -> deg -> dinv; dz0 = {dinv, z0}     (196 blocks x 512 thr)
//   prop1:    z1 = P(z0)+c1      prop2: out = P(z1)+c2  (196 blocks x 512 thr)
// P(z)[n] = dinv[n]*sum_e(ew_e*dinv[src_e]*z[src_e]) + dinv[n]^2*z[n]
// R15 lessons: coarse buckets (196) give full-line runs at high bin-block counts;
// tail kernels need >=2 waves/SIMD for latency hiding. R12: no grid.sync.
// N=50000, E=800000, IN=256, HID=128, OUT=1. All arithmetic f32.

static constexpr int NN   = 50000;
static constexpr int NE   = 800000;
static constexpr int IND  = 256;
static constexpr int HD   = 128;
static constexpr int NNP  = 50048;

static constexpr int NBUK = 196;            // ceil(NN/256); bucket = dst >> 8
static constexpr int BCAP = 5120;           // mean fill 4096, +16 sigma
static constexpr int BIN_BLOCKS  = 512;     // 2 blocks/CU during the bin tail
static constexpr int EPB         = (NE + BIN_BLOCKS - 1) / BIN_BLOCKS;  // 1563
static constexpr int SLOTS       = (EPB + 255) / 256;                   // 7
static constexpr int GEMV_BLOCKS = 3125;    // 16 nodes per block (exact)

// ---------------- prep: fold weights + zero bucket cursors (one block) ----------------

__global__ __launch_bounds__(256) void prep_kernel(
        const float* __restrict__ W1, const float* __restrict__ b1,
        const float* __restrict__ W2, const float* __restrict__ b2,
        const float* __restrict__ Wc, const float* __restrict__ bc,
        float* __restrict__ w1c, float* __restrict__ consts,
        int* __restrict__ gcur) {
    __shared__ float s_w2c[HD];
    const int t = threadIdx.x;
    if (t < NBUK) gcur[t] = 0;
    if (t < HD) {
        float s = 0.f;
        for (int j = 0; j < HD; j++) s += W2[t * HD + j] * Wc[j];
        s_w2c[t] = s;
    }
    __syncthreads();
    {   // t in [0,256) == IND
        float s = 0.f;
        for (int k = 0; k < HD; k++) s += W1[t * HD + k] * s_w2c[k];
        w1c[t] = s;
    }
    if (t == 0) {
        float c1 = 0.f, c2 = 0.f;
        for (int k = 0; k < HD; k++) c1 += b1[k] * s_w2c[k];
        for (int j = 0; j < HD; j++) c2 += b2[j] * Wc[j];
        consts[0] = c1;
        consts[1] = c2 + bc[0];
    }
}

// ---------------- fused edge binning (reg-staged, first) + GEMV ----------------
// Bin blocks [0,512): stage ~1563 edges in registers (one read pass), LDS histogram
// over 196 coarse buckets, reserve global ranges (1 atomic per block-bucket,
// ~8-record = 64B runs), write 8B records {src u16 | dloc u8 | buk u8, ew f32}.
// GEMV blocks: one wave per 4 nodes, branchless, 4 loads up-front (ILP).

__global__ __launch_bounds__(256) void gemv_bin(
        const float* __restrict__ x, const float* __restrict__ w1c,
        float* __restrict__ z0,
        const int* __restrict__ src, const int* __restrict__ dst,
        const float* __restrict__ ew,
        int* __restrict__ gcur, uint2* __restrict__ bins) {
    __shared__ int hist[NBUK];
    __shared__ int cur[NBUK];

    if (blockIdx.x < BIN_BLOCKS) {
        const int t    = threadIdx.x;
        const int base = blockIdx.x * EPB;
        const int lim  = min(EPB, NE - base);   // last block partial
        uint  key[SLOTS];
        float wv[SLOTS];
        if (t < NBUK) hist[t] = 0;
        __syncthreads();
#pragma unroll
        for (int k = 0; k < SLOTS; k++) {
            const int off = k * 256 + t;
            if (off < lim) {
                const int e = base + off;
                const int d = dst[e];
                const int b = d >> 8;
                key[k] = (uint)src[e] | (((uint)d & 255u) << 16) | ((uint)b << 24);
                wv[k]  = ew[e];
                atomicAdd(&hist[b], 1);
            } else {
                key[k] = 0xFFFFFFFFu;
            }
        }
        __syncthreads();
        if (t < NBUK) {
            const int h = hist[t];
            cur[t] = h ? atomicAdd(&gcur[t], h) : 0;
        }
        __syncthreads();
#pragma unroll
        for (int k = 0; k < SLOTS; k++) {
            if (key[k] != 0xFFFFFFFFu) {
                const int b = key[k] >> 24;
                const int p = atomicAdd(&cur[b], 1);
                if (p < BCAP)
                    bins[(size_t)b * BCAP + p] =
                        make_uint2(key[k] & 0xFFFFFFu, __float_as_uint(wv[k]));
            }
        }
    } else {
        const int wid  = threadIdx.x >> 6;
        const int lane = threadIdx.x & 63;
        const int n0   = (blockIdx.x - BIN_BLOCKS) * 16 + wid * 4;   // exact: no bounds
        const float4 wv = ((const float4*)w1c)[lane];
        const float4 x0 = *((const float4*)(x + (size_t)(n0 + 0) * IND) + lane);
        const float4 x1 = *((const float4*)(x + (size_t)(n0 + 1) * IND) + lane);
        const float4 x2 = *((const float4*)(x + (size_t)(n0 + 2) * IND) + lane);
        const float4 x3 = *((const float4*)(x + (size_t)(n0 + 3) * IND) + lane);
        float p0 = x0.x * wv.x + x0.y * wv.y + x0.z * wv.z + x0.w * wv.w;
        float p1 = x1.x * wv.x + x1.y * wv.y + x1.z * wv.z + x1.w * wv.w;
        float p2 = x2.x * wv.x + x2.y * wv.y + x2.z * wv.z + x2.w * wv.w;
        float p3 = x3.x * wv.x + x3.y * wv.y + x3.z * wv.z + x3.w * wv.w;
#pragma unroll
        for (int off = 32; off; off >>= 1) {
            p0 += __shfl_down(p0, off);
            p1 += __shfl_down(p1, off);
            p2 += __shfl_down(p2, off);
            p3 += __shfl_down(p3, off);
        }
        if (lane == 0) {
            z0[n0 + 0] = p0;
            z0[n0 + 1] = p1;
            z0[n0 + 2] = p2;
            z0[n0 + 3] = p3;
        }
    }
}

// ---------------- bindeg: bins -> dinv, interleave dz0 = {dinv, z0} ----------------
// one 256-node bucket per block, 512 threads (2 waves/SIMD), 256-slot LDS acc.

__global__ __launch_bounds__(512) void bindeg_kernel(
        const int* __restrict__ gcur, const uint2* __restrict__ bins,
        const float* __restrict__ z0, float2* __restrict__ dz0) {
    __shared__ float acc[256];
    const int b = blockIdx.x, t = threadIdx.x;
    if (t < 256) acc[t] = 0.f;
    __syncthreads();
    const int cnt = min(gcur[b], BCAP);
    for (int r = t; r < cnt; r += 512) {
        const uint2 q = bins[(size_t)b * BCAP + r];
        atomicAdd(&acc[(q.x >> 16) & 255u], __uint_as_float(q.y));
    }
    __syncthreads();
    if (t < 256) {
        const int n = b * 256 + t;
        if (n < NN) dz0[n] = make_float2(rsqrtf(acc[t] + 1.0f), z0[n]);
    }
}

// ---------------- prop: one bucket per block, 512 threads, 256-slot LDS acc ---------
// zout[n] = acc[n]*dinv[n] + z[n]*dinv[n]^2 + consts[cidx]

template<bool LAST>
__global__ __launch_bounds__(512) void prop_kernel(
        const int* __restrict__ gcur, const uint2* __restrict__ bins,
        const float2* __restrict__ dzin, const float* __restrict__ consts,
        int cidx, float2* __restrict__ dzout, float* __restrict__ fout) {
    __shared__ float acc[256];
    const int b = blockIdx.x, t = threadIdx.x;
    if (t < 256) acc[t] = 0.f;
    __syncthreads();
    const int cnt = min(gcur[b], BCAP);
    for (int r = t; r < cnt; r += 512) {
        const uint2 q = bins[(size_t)b * BCAP + r];
        const float2 sz = dzin[q.x & 0xFFFFu];          // {dinv[s], z[s]} — L2-resident
        atomicAdd(&acc[(q.x >> 16) & 255u], __uint_as_float(q.y) * sz.x * sz.y);
    }
    __syncthreads();
    if (t < 256) {
        const int n = b * 256 + t;
        if (n < NN) {
            const float2 me = dzin[n];
            const float v = acc[t] * me.x + me.y * me.x * me.x + consts[cidx];
            if (LAST) fout[n] = v;
            else      dzout[n] = make_float2(me.x, v);
        }
    }
}

// ---------------- launch ----------------

extern "C" void kernel_launch(void* const* d_in, const int* in_sizes, int n_in,
                              void* d_out, int out_size, void* d_ws, size_t ws_size,
                              hipStream_t stream) {
    const float* x   = (const float*)d_in[0];
    const int*   ei  = (const int*)d_in[1];     // [2][E] int32
    const float* ew  = (const float*)d_in[2];
    const float* W1  = (const float*)d_in[3];
    const float* b1  = (const float*)d_in[4];
    const float* W2  = (const float*)d_in[5];
    const float* b2  = (const float*)d_in[6];
    const float* Wc  = (const float*)d_in[7];
    const float* bc  = (const float*)d_in[8];
    const int* src = ei;
    const int* dst = ei + NE;
    float* out = (float*)d_out;

    // workspace layout (~9.6 MB)
    uint2*  bins   = (uint2*)d_ws;                           // NBUK*BCAP uint2 (8.0 MB)
    float2* dz0    = (float2*)(bins + (size_t)NBUK * BCAP);  // NNP float2
    float2* dz1    = dz0 + NNP;                              // NNP float2
    float*  z0     = (float*)(dz1 + NNP);                    // NNP f32
    float*  w1c    = z0 + NNP;                               // 256 f32
    float*  consts = w1c + 256;                              // 2 f32 {c1, c2}
    int*    gcur   = (int*)(consts + 64);                    // NBUK int

    // ---- fold weights + zero cursors ----
    prep_kernel<<<1, 256, 0, stream>>>(W1, b1, W2, b2, Wc, bc, w1c, consts, gcur);

    // ---- edge binning (first blocks, reg-staged) overlapped with z0 = x @ w1c ----
    gemv_bin<<<BIN_BLOCKS + GEMV_BLOCKS, 256, 0, stream>>>(
        x, w1c, z0, src, dst, ew, gcur, bins);

    // ---- dinv from bins, build {dinv, z0} ----
    bindeg_kernel<<<NBUK, 512, 0, stream>>>(gcur, bins, z0, dz0);

    // ---- two scalar propagations ----
    prop_kernel<false><<<NBUK, 512, 0, stream>>>(gcur, bins, dz0, consts, 0, dz1, nullptr);
    prop_kernel<true><<<NBUK, 512, 0, stream>>>(gcur, bins, dz1, consts, 1, nullptr, out);
}

// Round 17
// 58.522 us; speedup vs baseline: 1.0628x; 1.0628x over previous
//
#include <hip/hip_runtime.h>

// FairINV 2-layer GCN + linear head — linear collapse + bucket-binned propagation.
//   w2c = W2@Wc; w1c = W1@w2c; c1 = b1.w2c; c2 = b2.Wc + bc      (prep, 1 block)
//   gemv_bin (512 thr): bin edges by bucket dst>>8 (256 bin units, 7 staged rounds,
//             FIRST, ~16-record/128B runs) || z0 = x@w1c (GEMV, 32 nodes/block)
//   bindeg:   bins -> deg -> dinv; dz0 = {dinv, z0}     (196 blocks x 256 thr)
//   prop1:    z1 = P(z0)+c1      prop2: out = P(z1)+c2  (196 blocks x 256 thr)
// P(z)[n] = dinv[n]*sum_e(ew_e*dinv[src_e]*z[src_e]) + dinv[n]^2*z[n]
// R16 lessons: 512 bin blocks halves run length (regression) and 512-thr tail
// doubles LDS-atomic contention (regression) — both reverted. This round halves
// the bin SERIAL path instead (512-thr bin blocks, same 256-block count).
// R12: no cooperative grid.sync. All arithmetic f32.
// N=50000, E=800000, IN=256, HID=128, OUT=1.

static constexpr int NN   = 50000;
static constexpr int NE   = 800000;
static constexpr int IND  = 256;
static constexpr int HD   = 128;
static constexpr int NNP  = 50048;

static constexpr int NBUK = 196;            // ceil(NN/256); bucket = dst >> 8
static constexpr int BCAP = 5120;           // mean fill 4096, +16 sigma
static constexpr int BIN_BLOCKS  = 256;     // keeps ~16-record (128B) runs
static constexpr int EPB         = NE / BIN_BLOCKS;   // 3125 (exact)
static constexpr int SLOTS       = (EPB + 511) / 512; // 7 staging rounds (512 thr)
static constexpr int GEMV_BLOCKS = (NN + 31) / 32;    // 1563; 32 nodes per block

// ---------------- prep: fold weights + zero bucket cursors (one block) ----------------

__global__ __launch_bounds__(256) void prep_kernel(
        const float* __restrict__ W1, const float* __restrict__ b1,
        const float* __restrict__ W2, const float* __restrict__ b2,
        const float* __restrict__ Wc, const float* __restrict__ bc,
        float* __restrict__ w1c, float* __restrict__ consts,
        int* __restrict__ gcur) {
    __shared__ float s_w2c[HD];
    const int t = threadIdx.x;
    if (t < NBUK) gcur[t] = 0;
    if (t < HD) {
        float s = 0.f;
        for (int j = 0; j < HD; j++) s += W2[t * HD + j] * Wc[j];
        s_w2c[t] = s;
    }
    __syncthreads();
    {   // t in [0,256) == IND
        float s = 0.f;
        for (int k = 0; k < HD; k++) s += W1[t * HD + k] * s_w2c[k];
        w1c[t] = s;
    }
    if (t == 0) {
        float c1 = 0.f, c2 = 0.f;
        for (int k = 0; k < HD; k++) c1 += b1[k] * s_w2c[k];
        for (int j = 0; j < HD; j++) c2 += b2[j] * Wc[j];
        consts[0] = c1;
        consts[1] = c2 + bc[0];
    }
}

// ---------------- fused edge binning (reg-staged, first) + GEMV — 512 threads --------
// Bin blocks [0,256): stage 3125 edges in 7 register rounds, LDS histogram over
// 196 coarse buckets, reserve global ranges (1 atomic per block-bucket,
// ~16-record = 128B runs), write 8B records {src u16 | dloc u8 | buk u8, ew f32}.
// GEMV blocks: 8 waves x 4 nodes = 32 nodes/block, branchless fast path.

__global__ __launch_bounds__(512) void gemv_bin(
        const float* __restrict__ x, const float* __restrict__ w1c,
        float* __restrict__ z0,
        const int* __restrict__ src, const int* __restrict__ dst,
        const float* __restrict__ ew,
        int* __restrict__ gcur, uint2* __restrict__ bins) {
    __shared__ int hist[NBUK];
    __shared__ int cur[NBUK];

    if (blockIdx.x < BIN_BLOCKS) {
        const int t    = threadIdx.x;
        const int base = blockIdx.x * EPB;
        uint  key[SLOTS];
        float wv[SLOTS];
        if (t < NBUK) hist[t] = 0;
        __syncthreads();
#pragma unroll
        for (int k = 0; k < SLOTS; k++) {
            const int off = k * 512 + t;
            if (off < EPB) {
                const int e = base + off;
                const int d = dst[e];
                const int b = d >> 8;
                key[k] = (uint)src[e] | (((uint)d & 255u) << 16) | ((uint)b << 24);
                wv[k]  = ew[e];
                atomicAdd(&hist[b], 1);
            } else {
                key[k] = 0xFFFFFFFFu;
            }
        }
        __syncthreads();
        if (t < NBUK) {
            const int h = hist[t];
            cur[t] = h ? atomicAdd(&gcur[t], h) : 0;
        }
        __syncthreads();
#pragma unroll
        for (int k = 0; k < SLOTS; k++) {
            if (key[k] != 0xFFFFFFFFu) {
                const int b = key[k] >> 24;
                const int p = atomicAdd(&cur[b], 1);
                if (p < BCAP)
                    bins[(size_t)b * BCAP + p] =
                        make_uint2(key[k] & 0xFFFFFFu, __float_as_uint(wv[k]));
            }
        }
    } else {
        const int wid  = threadIdx.x >> 6;
        const int lane = threadIdx.x & 63;
        const int n0   = (blockIdx.x - BIN_BLOCKS) * 32 + wid * 4;
        const float4 wv = ((const float4*)w1c)[lane];
        if (n0 + 4 <= NN) {
            const float4 x0 = *((const float4*)(x + (size_t)(n0 + 0) * IND) + lane);
            const float4 x1 = *((const float4*)(x + (size_t)(n0 + 1) * IND) + lane);
            const float4 x2 = *((const float4*)(x + (size_t)(n0 + 2) * IND) + lane);
            const float4 x3 = *((const float4*)(x + (size_t)(n0 + 3) * IND) + lane);
            float p0 = x0.x * wv.x + x0.y * wv.y + x0.z * wv.z + x0.w * wv.w;
            float p1 = x1.x * wv.x + x1.y * wv.y + x1.z * wv.z + x1.w * wv.w;
            float p2 = x2.x * wv.x + x2.y * wv.y + x2.z * wv.z + x2.w * wv.w;
            float p3 = x3.x * wv.x + x3.y * wv.y + x3.z * wv.z + x3.w * wv.w;
#pragma unroll
            for (int off = 32; off; off >>= 1) {
                p0 += __shfl_down(p0, off);
                p1 += __shfl_down(p1, off);
                p2 += __shfl_down(p2, off);
                p3 += __shfl_down(p3, off);
            }
            if (lane == 0) {
                z0[n0 + 0] = p0;
                z0[n0 + 1] = p1;
                z0[n0 + 2] = p2;
                z0[n0 + 3] = p3;
            }
        } else {
#pragma unroll
            for (int g = 0; g < 4; g++) {
                const int n = n0 + g;
                if (n < NN) {
                    const float4 xv = *((const float4*)(x + (size_t)n * IND) + lane);
                    float p = xv.x * wv.x + xv.y * wv.y + xv.z * wv.z + xv.w * wv.w;
#pragma unroll
                    for (int off = 32; off; off >>= 1) p += __shfl_down(p, off);
                    if (lane == 0) z0[n] = p;
                }
            }
        }
    }
}

// ---------------- bindeg: bins -> dinv, interleave dz0 = {dinv, z0} ----------------
// one 256-node bucket per block, 256 threads (R15-proven), 256-slot LDS acc.

__global__ __launch_bounds__(256) void bindeg_kernel(
        const int* __restrict__ gcur, const uint2* __restrict__ bins,
        const float* __restrict__ z0, float2* __restrict__ dz0) {
    __shared__ float acc[256];
    const int b = blockIdx.x, t = threadIdx.x;
    acc[t] = 0.f;
    __syncthreads();
    const int cnt = min(gcur[b], BCAP);
    for (int r = t; r < cnt; r += 256) {
        const uint2 q = bins[(size_t)b * BCAP + r];
        atomicAdd(&acc[(q.x >> 16) & 255u], __uint_as_float(q.y));
    }
    __syncthreads();
    const int n = b * 256 + t;
    if (n < NN) dz0[n] = make_float2(rsqrtf(acc[t] + 1.0f), z0[n]);
}

// ---------------- prop: one bucket per block, 256 threads, 256-slot LDS acc ---------
// zout[n] = acc[n]*dinv[n] + z[n]*dinv[n]^2 + consts[cidx]

template<bool LAST>
__global__ __launch_bounds__(256) void prop_kernel(
        const int* __restrict__ gcur, const uint2* __restrict__ bins,
        const float2* __restrict__ dzin, const float* __restrict__ consts,
        int cidx, float2* __restrict__ dzout, float* __restrict__ fout) {
    __shared__ float acc[256];
    const int b = blockIdx.x, t = threadIdx.x;
    acc[t] = 0.f;
    __syncthreads();
    const int cnt = min(gcur[b], BCAP);
    for (int r = t; r < cnt; r += 256) {
        const uint2 q = bins[(size_t)b * BCAP + r];
        const float2 sz = dzin[q.x & 0xFFFFu];          // {dinv[s], z[s]} — L2-resident
        atomicAdd(&acc[(q.x >> 16) & 255u], __uint_as_float(q.y) * sz.x * sz.y);
    }
    __syncthreads();
    const int n = b * 256 + t;
    if (n < NN) {
        const float2 me = dzin[n];
        const float v = acc[t] * me.x + me.y * me.x * me.x + consts[cidx];
        if (LAST) fout[n] = v;
        else      dzout[n] = make_float2(me.x, v);
    }
}

// ---------------- launch ----------------

extern "C" void kernel_launch(void* const* d_in, const int* in_sizes, int n_in,
                              void* d_out, int out_size, void* d_ws, size_t ws_size,
                              hipStream_t stream) {
    const float* x   = (const float*)d_in[0];
    const int*   ei  = (const int*)d_in[1];     // [2][E] int32
    const float* ew  = (const float*)d_in[2];
    const float* W1  = (const float*)d_in[3];
    const float* b1  = (const float*)d_in[4];
    const float* W2  = (const float*)d_in[5];
    const float* b2  = (const float*)d_in[6];
    const float* Wc  = (const float*)d_in[7];
    const float* bc  = (const float*)d_in[8];
    const int* src = ei;
    const int* dst = ei + NE;
    float* out = (float*)d_out;

    // workspace layout (~9.6 MB)
    uint2*  bins   = (uint2*)d_ws;                           // NBUK*BCAP uint2 (8.0 MB)
    float2* dz0    = (float2*)(bins + (size_t)NBUK * BCAP);  // NNP float2
    float2* dz1    = dz0 + NNP;                              // NNP float2
    float*  z0     = (float*)(dz1 + NNP);                    // NNP f32
    float*  w1c    = z0 + NNP;                               // 256 f32
    float*  consts = w1c + 256;                              // 2 f32 {c1, c2}
    int*    gcur   = (int*)(consts + 64);                    // NBUK int

    // ---- fold weights + zero cursors ----
    prep_kernel<<<1, 256, 0, stream>>>(W1, b1, W2, b2, Wc, bc, w1c, consts, gcur);

    // ---- edge binning (first blocks, reg-staged) overlapped with z0 = x @ w1c ----
    gemv_bin<<<BIN_BLOCKS + GEMV_BLOCKS, 512, 0, stream>>>(
        x, w1c, z0, src, dst, ew, gcur, bins);

    // ---- dinv from bins, build {dinv, z0} ----
    bindeg_kernel<<<NBUK, 256, 0, stream>>>(gcur, bins, z0, dz0);

    // ---- two scalar propagations ----
    prop_kernel<false><<<NBUK, 256, 0, stream>>>(gcur, bins, dz0, consts, 0, dz1, nullptr);
    prop_kernel<true><<<NBUK, 256, 0, stream>>>(gcur, bins, dz1, consts, 1, nullptr, out);
}